// Round 9
// baseline (264.322 us; speedup 1.0000x reference)
//
#include <hip/hip_runtime.h>
#include <hip/hip_bf16.h>

#define DOUT 64
#define DIN 128
#define NEG_SLOPE 0.2f
#define EPSV 1e-10f
#define LDA 136        // 128 + 8 bf16 pad
#define BKT_SHIFT 9    // 512 targets per coarse bucket
#define BKT_SIZE 512
#define PASSA_CHUNK 1536

typedef __attribute__((ext_vector_type(8))) __bf16 bf16x8;
typedef __attribute__((ext_vector_type(8))) unsigned short ushortx8;
typedef __attribute__((ext_vector_type(4))) float floatx4;

__device__ __forceinline__ float bf16_to_f32(unsigned short u) {
    return __uint_as_float(((unsigned int)u) << 16);
}
__device__ __forceinline__ unsigned short f32_to_bf16(float f) {
    __hip_bfloat16 h = __float2bfloat16(f);
    unsigned short u;
    __builtin_memcpy(&u, &h, 2);
    return u;
}
__device__ __forceinline__ unsigned int f32x2_to_bf16x2(float a, float b) {
    __hip_bfloat162 h = __float22bfloat162_rn(make_float2(a, b));
    unsigned int u;
    __builtin_memcpy(&u, &h, 4);
    return u;
}

// ---------------------------------------------------------------------------
// Kernel 1: Wh = x @ W via bf16 MFMA; fused s_src, s_tgt. Wh stored bf16.
// ---------------------------------------------------------------------------
__global__ __launch_bounds__(256) void gat_gemm_scores(
    const float* __restrict__ x, const float* __restrict__ W,
    const float* __restrict__ a, unsigned short* __restrict__ Wh,
    float* __restrict__ ssrc, float* __restrict__ stgt, int N)
{
    __shared__ unsigned short A_sh[64 * LDA];
    __shared__ unsigned short B_sh[64 * LDA];

    const int tid = threadIdx.x;
    const int rowbase = blockIdx.x * 64;

    for (int idx = tid; idx < DIN * DOUT; idx += 256) {
        int k = idx >> 6, n = idx & 63;
        B_sh[n * LDA + k] = f32_to_bf16(W[idx]);
    }
    for (int it = 0; it < 8; ++it) {
        int flat = it * 1024 + tid * 4;
        int row = flat >> 7, k = flat & 127;
        int grow = rowbase + row;
        float4 v = make_float4(0.f, 0.f, 0.f, 0.f);
        if (grow < N) v = *(const float4*)&x[(size_t)grow * DIN + k];
        uint2 packed = make_uint2(f32x2_to_bf16x2(v.x, v.y),
                                  f32x2_to_bf16x2(v.z, v.w));
        *(uint2*)&A_sh[row * LDA + k] = packed;
    }
    __syncthreads();

    const int lane = tid & 63;
    const int wv   = tid >> 6;
    const int c16  = lane & 15;
    const int quad = lane >> 4;

    floatx4 acc[4] = {floatx4{0,0,0,0}, floatx4{0,0,0,0},
                      floatx4{0,0,0,0}, floatx4{0,0,0,0}};

    const int arow = (wv * 16 + c16) * LDA;
    #pragma unroll
    for (int kk = 0; kk < 4; ++kk) {
        const int koff = kk * 32 + quad * 8;
        bf16x8 af = __builtin_bit_cast(bf16x8, *(const ushortx8*)&A_sh[arow + koff]);
        #pragma unroll
        for (int nt = 0; nt < 4; ++nt) {
            bf16x8 bf = __builtin_bit_cast(bf16x8,
                           *(const ushortx8*)&B_sh[(nt * 16 + c16) * LDA + koff]);
            acc[nt] = __builtin_amdgcn_mfma_f32_16x16x32_bf16(af, bf, acc[nt], 0, 0, 0);
        }
    }

    float asrc_v[4], atgt_v[4];
    #pragma unroll
    for (int nt = 0; nt < 4; ++nt) {
        asrc_v[nt] = a[nt * 16 + c16];
        atgt_v[nt] = a[64 + nt * 16 + c16];
    }
    const int rbase = rowbase + wv * 16 + quad * 4;
    #pragma unroll
    for (int r = 0; r < 4; ++r) {
        int row = rbase + r;
        if (row < N) {
            #pragma unroll
            for (int nt = 0; nt < 4; ++nt)
                Wh[(size_t)row * DOUT + nt * 16 + c16] = f32_to_bf16(acc[nt][r]);
        }
    }
    #pragma unroll
    for (int r = 0; r < 4; ++r) {
        float ps = 0.f, pt = 0.f;
        #pragma unroll
        for (int nt = 0; nt < 4; ++nt) {
            ps += acc[nt][r] * asrc_v[nt];
            pt += acc[nt][r] * atgt_v[nt];
        }
        #pragma unroll
        for (int m = 1; m < 16; m <<= 1) {
            ps += __shfl_xor(ps, m);
            pt += __shfl_xor(pt, m);
        }
        if (c16 == 0) {
            int row = rbase + r;
            if (row < N) { ssrc[row] = ps; stgt[row] = pt; }
        }
    }
}

// ---------------------------------------------------------------------------
// Kernel 2: coarse bucket histogram (LDS hist, 1 global atomic per block/bucket).
// ---------------------------------------------------------------------------
__global__ __launch_bounds__(256) void gat_bhist(
    const int* __restrict__ ei, int* __restrict__ bcnt, int E)
{
    __shared__ int lh[256];
    const int tid = threadIdx.x;
    lh[tid] = 0;
    __syncthreads();
    int base = blockIdx.x * 4096;
    #pragma unroll
    for (int j = 0; j < 4; ++j) {
        int e4 = base + j * 1024 + tid * 4;
        if (e4 + 3 < E) {
            int4 t = *(const int4*)&ei[E + e4];
            atomicAdd(&lh[t.x >> BKT_SHIFT], 1);
            atomicAdd(&lh[t.y >> BKT_SHIFT], 1);
            atomicAdd(&lh[t.z >> BKT_SHIFT], 1);
            atomicAdd(&lh[t.w >> BKT_SHIFT], 1);
        } else {
            for (int e = e4; e < E; ++e) atomicAdd(&lh[ei[E + e] >> BKT_SHIFT], 1);
        }
    }
    __syncthreads();
    if (lh[tid] > 0) atomicAdd(&bcnt[tid], lh[tid]);
}

// ---------------------------------------------------------------------------
// Kernel 3: tiny scan of 256 bucket counts -> bkt_base[257], seed bcur.
// ---------------------------------------------------------------------------
__global__ __launch_bounds__(256) void gat_bscan(
    const int* __restrict__ bcnt, int* __restrict__ bkt_base,
    int* __restrict__ bcur, int E)
{
    __shared__ int lds[256];
    int i = threadIdx.x;
    lds[i] = bcnt[i];
    __syncthreads();
    if (i == 0) {
        int acc = 0;
        for (int j = 0; j < 256; ++j) { int c = lds[j]; lds[j] = acc; acc += c; }
    }
    __syncthreads();
    bkt_base[i] = lds[i];
    bcur[i] = lds[i];
    if (i == 0) bkt_base[256] = E;
}

// ---------------------------------------------------------------------------
// Kernel 4 (pass A): two-pass count-then-place coarse scatter. LDS = 3 KB
// (no staging array): pass 1 counts buckets, block reserves contiguous global
// ranges per bucket, pass 2 recomputes p and stores records directly to
// global at base[b] + rank. Occupancy-bound no more.
// ---------------------------------------------------------------------------
__global__ __launch_bounds__(256) void gat_binA(
    const int* __restrict__ ei, const float* __restrict__ ew,
    const float* __restrict__ ssrc, const float* __restrict__ stgt,
    int* __restrict__ bcur, int2* __restrict__ staged_g, int E)
{
    __shared__ int lcnt[256];
    __shared__ int lbase[256];
    const int tid = threadIdx.x;
    lcnt[tid] = 0;
    __syncthreads();

    const int base = blockIdx.x * PASSA_CHUNK;

    // pass 1: count buckets (int2 vectorized target reads)
    #pragma unroll
    for (int j = 0; j < PASSA_CHUNK / 512; ++j) {
        int e2 = base + j * 512 + tid * 2;
        if (e2 + 1 < E) {
            int2 tt = *(const int2*)&ei[E + e2];
            atomicAdd(&lcnt[tt.x >> BKT_SHIFT], 1);
            atomicAdd(&lcnt[tt.y >> BKT_SHIFT], 1);
        } else {
            for (int e = e2; e < E; ++e) atomicAdd(&lcnt[ei[E + e] >> BKT_SHIFT], 1);
        }
    }
    __syncthreads();

    int c = lcnt[tid];
    lbase[tid] = (c > 0) ? atomicAdd(&bcur[tid], c) : 0;
    lcnt[tid] = 0;   // reuse as rank cursor
    __syncthreads();

    // pass 2: compute p, place record at reserved position
    #pragma unroll
    for (int j = 0; j < PASSA_CHUNK / 512; ++j) {
        int e2 = base + j * 512 + tid * 2;
        if (e2 + 1 < E) {
            int2 ss = *(const int2*)&ei[e2];
            int2 tt = *(const int2*)&ei[E + e2];
            float2 ww = *(const float2*)&ew[e2];
            #pragma unroll
            for (int u = 0; u < 2; ++u) {
                int s = (u == 0) ? ss.x : ss.y;
                int t = (u == 0) ? tt.x : tt.y;
                float w = (u == 0) ? ww.x : ww.y;
                float v = ssrc[s] + stgt[t];
                v = (v > 0.f) ? v : NEG_SLOPE * v;
                v *= w;
                float p = __expf(v);
                int b = t >> BKT_SHIFT;
                int r = atomicAdd(&lcnt[b], 1);
                staged_g[lbase[b] + r] =
                    make_int2(s | ((t & (BKT_SIZE - 1)) << 17), __float_as_int(p));
            }
        } else {
            for (int e = e2; e < E; ++e) {
                int s = ei[e];
                int t = ei[E + e];
                float v = ssrc[s] + stgt[t];
                v = (v > 0.f) ? v : NEG_SLOPE * v;
                v *= ew[e];
                float p = __expf(v);
                int b = t >> BKT_SHIFT;
                int r = atomicAdd(&lcnt[b], 1);
                staged_g[lbase[b] + r] =
                    make_int2(s | ((t & (BKT_SIZE - 1)) << 17), __float_as_int(p));
            }
        }
    }
}

// ---------------------------------------------------------------------------
// Kernel 5 (pass B): fine sort within a bucket, all in LDS.
// ---------------------------------------------------------------------------
__global__ __launch_bounds__(256) void gat_binB(
    const int2* __restrict__ staged_g, const int* __restrict__ bkt_base,
    int* __restrict__ row_ptr, int2* __restrict__ sorted_sp, int N, int E)
{
    __shared__ int lcnt[BKT_SIZE];
    __shared__ int lcur[BKT_SIZE];
    __shared__ int lscan[256];

    const int b = blockIdx.x;
    const int tid = threadIdx.x;
    const int tbase = b << BKT_SHIFT;
    const int beg = bkt_base[b];
    const int end = bkt_base[b + 1];

    lcnt[tid] = 0; lcnt[tid + 256] = 0;
    __syncthreads();

    for (int i = beg + tid; i < end; i += 256) {
        int tl = (staged_g[i].x >> 17) & (BKT_SIZE - 1);
        atomicAdd(&lcnt[tl], 1);
    }
    __syncthreads();

    int c0 = lcnt[2 * tid], c1 = lcnt[2 * tid + 1];
    int pair = c0 + c1;
    lscan[tid] = pair;
    __syncthreads();
    for (int off = 1; off < 256; off <<= 1) {
        int t = (tid >= off) ? lscan[tid - off] : 0;
        __syncthreads();
        lscan[tid] += t;
        __syncthreads();
    }
    int excl = lscan[tid] - pair;
    lcur[2 * tid]     = beg + excl;
    lcur[2 * tid + 1] = beg + excl + c0;
    __syncthreads();

    #pragma unroll
    for (int j = 0; j < 2; ++j) {
        int tl = tid + j * 256;
        int g = tbase + tl;
        if (g < N) row_ptr[g] = lcur[tl];
    }
    if (tid == 0 && b == gridDim.x - 1) row_ptr[N] = E;

    for (int i = beg + tid; i < end; i += 256) {
        int2 rec = staged_g[i];
        int tl = (rec.x >> 17) & (BKT_SIZE - 1);
        int pos = atomicAdd(&lcur[tl], 1);
        sorted_sp[pos] = make_int2(rec.x & 0x1FFFF, rec.y);
    }
}

// ---------------------------------------------------------------------------
// Kernel 6: segmented reduction. One wave per target; 8 sub-groups of 8 lanes,
// each sub owns one edge per iteration; each lane loads ushort8 (16 B).
// ---------------------------------------------------------------------------
__global__ __launch_bounds__(256) void gat_aggregate_csr(
    const int* __restrict__ row_ptr, const int2* __restrict__ sorted_sp,
    const unsigned short* __restrict__ Wh, float* __restrict__ out, int N)
{
    int t = blockIdx.x * 4 + (threadIdx.x >> 6);
    if (t >= N) return;
    int lane = threadIdx.x & 63;
    int sub  = lane >> 3;    // edge slot 0..7
    int c8   = lane & 7;     // channel block: channels c8*8 .. c8*8+7

    int beg = row_ptr[t], end = row_ptr[t + 1];

    float acc[8] = {0.f, 0.f, 0.f, 0.f, 0.f, 0.f, 0.f, 0.f};
    float psum = 0.f;

    int i = beg + sub;
    for (; i + 8 < end; i += 16) {
        int2 spA = sorted_sp[i];
        int2 spB = sorted_sp[i + 8];
        float pA = __int_as_float(spA.y);
        float pB = __int_as_float(spB.y);
        ushortx8 wA = *(const ushortx8*)&Wh[(size_t)spA.x * DOUT + c8 * 8];
        ushortx8 wB = *(const ushortx8*)&Wh[(size_t)spB.x * DOUT + c8 * 8];
        #pragma unroll
        for (int j = 0; j < 8; ++j) acc[j] += pA * bf16_to_f32(wA[j]);
        psum += pA;
        #pragma unroll
        for (int j = 0; j < 8; ++j) acc[j] += pB * bf16_to_f32(wB[j]);
        psum += pB;
    }
    if (i < end) {
        int2 sp = sorted_sp[i];
        float p = __int_as_float(sp.y);
        ushortx8 w = *(const ushortx8*)&Wh[(size_t)sp.x * DOUT + c8 * 8];
        #pragma unroll
        for (int j = 0; j < 8; ++j) acc[j] += p * bf16_to_f32(w[j]);
        psum += p;
    }

    #pragma unroll
    for (int m = 8; m < 64; m <<= 1) {
        #pragma unroll
        for (int j = 0; j < 8; ++j) acc[j] += __shfl_xor(acc[j], m);
        psum += __shfl_xor(psum, m);
    }

    if (sub == 0) {
        float inv = 1.0f / (psum + EPSV);
        float4 o0 = make_float4(acc[0] * inv, acc[1] * inv, acc[2] * inv, acc[3] * inv);
        float4 o1 = make_float4(acc[4] * inv, acc[5] * inv, acc[6] * inv, acc[7] * inv);
        *(float4*)&out[(size_t)t * DOUT + c8 * 8]     = o0;
        *(float4*)&out[(size_t)t * DOUT + c8 * 8 + 4] = o1;
    }
}

extern "C" void kernel_launch(void* const* d_in, const int* in_sizes, int n_in,
                              void* d_out, int out_size, void* d_ws, size_t ws_size,
                              hipStream_t stream) {
    const float* x  = (const float*)d_in[0];
    const int*   ei = (const int*)d_in[1];
    const float* ew = (const float*)d_in[2];
    const float* W  = (const float*)d_in[3];
    const float* a  = (const float*)d_in[4];
    const int N = in_sizes[0] / DIN;
    const int E = in_sizes[2];
    float* out = (float*)d_out;

    char* wsb = (char*)d_ws;
    unsigned short* Wh = (unsigned short*)wsb;      wsb += (size_t)N * DOUT * 2;
    float* ssrc      = (float*)wsb;                 wsb += (size_t)N * 4;
    float* stgt      = (float*)wsb;                 wsb += (size_t)N * 4;
    int*   row_ptr   = (int*)wsb;                   wsb += (size_t)(N + 1) * 4;
    int*   bcnt      = (int*)wsb;                   wsb += 257 * 4;
    int*   bkt_base  = (int*)wsb;                   wsb += 257 * 4;
    int*   bcur      = (int*)wsb;                   wsb += 256 * 4;
    wsb = (char*)(((uintptr_t)wsb + 15) & ~(uintptr_t)15);
    int2*  staged_g  = (int2*)wsb;                  wsb += (size_t)E * 8;
    int2*  sorted_sp = (int2*)wsb;                  wsb += (size_t)E * 8;

    const int nbk = (N + BKT_SIZE - 1) >> BKT_SHIFT;

    (void)hipMemsetAsync(bcnt, 0, 257 * sizeof(int), stream);

    gat_gemm_scores<<<(N + 63) / 64, 256, 0, stream>>>(x, W, a, Wh, ssrc, stgt, N);
    gat_bhist <<<(E + 4095) / 4096, 256, 0, stream>>>(ei, bcnt, E);
    gat_bscan <<<1, 256, 0, stream>>>(bcnt, bkt_base, bcur, E);
    gat_binA  <<<(E + PASSA_CHUNK - 1) / PASSA_CHUNK, 256, 0, stream>>>(
                  ei, ew, ssrc, stgt, bcur, staged_g, E);
    gat_binB  <<<nbk, 256, 0, stream>>>(staged_g, bkt_base, row_ptr, sorted_sp, N, E);
    gat_aggregate_csr<<<(N + 3) / 4, 256, 0, stream>>>(row_ptr, sorted_sp, Wh, out, N);
}

// Round 10
// 238.959 us; speedup vs baseline: 1.1061x; 1.1061x over previous
//
#include <hip/hip_runtime.h>
#include <hip/hip_bf16.h>

#define DOUT 64
#define DIN 128
#define NEG_SLOPE 0.2f
#define EPSV 1e-10f
#define LDA 136        // 128 + 8 bf16 pad
#define BKT_SHIFT 9    // 512 targets per coarse bucket
#define BKT_SIZE 512
#define PASSA_CHUNK 3072
#define CAP 24         // staging slots per bucket per block (binA): 48 KB

typedef __attribute__((ext_vector_type(8))) __bf16 bf16x8;
typedef __attribute__((ext_vector_type(8))) unsigned short ushortx8;
typedef __attribute__((ext_vector_type(4))) float floatx4;

__device__ __forceinline__ float bf16_to_f32(unsigned short u) {
    return __uint_as_float(((unsigned int)u) << 16);
}
__device__ __forceinline__ unsigned short f32_to_bf16(float f) {
    __hip_bfloat16 h = __float2bfloat16(f);
    unsigned short u;
    __builtin_memcpy(&u, &h, 2);
    return u;
}
__device__ __forceinline__ unsigned int f32x2_to_bf16x2(float a, float b) {
    __hip_bfloat162 h = __float22bfloat162_rn(make_float2(a, b));
    unsigned int u;
    __builtin_memcpy(&u, &h, 4);
    return u;
}
__device__ __forceinline__ float leaky_exp(float vs, float vt, float w) {
    float v = vs + vt;
    v = (v > 0.f) ? v : NEG_SLOPE * v;
    return __expf(v * w);
}

// ---------------------------------------------------------------------------
// Kernel 1: Wh = x @ W via bf16 MFMA; fused s_src, s_tgt. Wh stored bf16.
// ---------------------------------------------------------------------------
__global__ __launch_bounds__(256) void gat_gemm_scores(
    const float* __restrict__ x, const float* __restrict__ W,
    const float* __restrict__ a, unsigned short* __restrict__ Wh,
    float* __restrict__ ssrc, float* __restrict__ stgt, int N)
{
    __shared__ unsigned short A_sh[64 * LDA];
    __shared__ unsigned short B_sh[64 * LDA];

    const int tid = threadIdx.x;
    const int rowbase = blockIdx.x * 64;

    for (int idx = tid; idx < DIN * DOUT; idx += 256) {
        int k = idx >> 6, n = idx & 63;
        B_sh[n * LDA + k] = f32_to_bf16(W[idx]);
    }
    for (int it = 0; it < 8; ++it) {
        int flat = it * 1024 + tid * 4;
        int row = flat >> 7, k = flat & 127;
        int grow = rowbase + row;
        float4 v = make_float4(0.f, 0.f, 0.f, 0.f);
        if (grow < N) v = *(const float4*)&x[(size_t)grow * DIN + k];
        uint2 packed = make_uint2(f32x2_to_bf16x2(v.x, v.y),
                                  f32x2_to_bf16x2(v.z, v.w));
        *(uint2*)&A_sh[row * LDA + k] = packed;
    }
    __syncthreads();

    const int lane = tid & 63;
    const int wv   = tid >> 6;
    const int c16  = lane & 15;
    const int quad = lane >> 4;

    floatx4 acc[4] = {floatx4{0,0,0,0}, floatx4{0,0,0,0},
                      floatx4{0,0,0,0}, floatx4{0,0,0,0}};

    const int arow = (wv * 16 + c16) * LDA;
    #pragma unroll
    for (int kk = 0; kk < 4; ++kk) {
        const int koff = kk * 32 + quad * 8;
        bf16x8 af = __builtin_bit_cast(bf16x8, *(const ushortx8*)&A_sh[arow + koff]);
        #pragma unroll
        for (int nt = 0; nt < 4; ++nt) {
            bf16x8 bf = __builtin_bit_cast(bf16x8,
                           *(const ushortx8*)&B_sh[(nt * 16 + c16) * LDA + koff]);
            acc[nt] = __builtin_amdgcn_mfma_f32_16x16x32_bf16(af, bf, acc[nt], 0, 0, 0);
        }
    }

    float asrc_v[4], atgt_v[4];
    #pragma unroll
    for (int nt = 0; nt < 4; ++nt) {
        asrc_v[nt] = a[nt * 16 + c16];
        atgt_v[nt] = a[64 + nt * 16 + c16];
    }
    const int rbase = rowbase + wv * 16 + quad * 4;
    #pragma unroll
    for (int r = 0; r < 4; ++r) {
        int row = rbase + r;
        if (row < N) {
            #pragma unroll
            for (int nt = 0; nt < 4; ++nt)
                Wh[(size_t)row * DOUT + nt * 16 + c16] = f32_to_bf16(acc[nt][r]);
        }
    }
    #pragma unroll
    for (int r = 0; r < 4; ++r) {
        float ps = 0.f, pt = 0.f;
        #pragma unroll
        for (int nt = 0; nt < 4; ++nt) {
            ps += acc[nt][r] * asrc_v[nt];
            pt += acc[nt][r] * atgt_v[nt];
        }
        #pragma unroll
        for (int m = 1; m < 16; m <<= 1) {
            ps += __shfl_xor(ps, m);
            pt += __shfl_xor(pt, m);
        }
        if (c16 == 0) {
            int row = rbase + r;
            if (row < N) { ssrc[row] = ps; stgt[row] = pt; }
        }
    }
}

// ---------------------------------------------------------------------------
// Kernel 2: coarse bucket histogram + edge logits. Streams edges (4/thread
// per batch, 16/thread total), gathers ssrc/stgt with 8 loads in flight,
// stores p coalesced, LDS hist -> 1 global atomic per block/bucket.
// No dependent chains: hist atomics don't return, p-store depends only on
// the gathers.
// ---------------------------------------------------------------------------
__global__ __launch_bounds__(256) void gat_bhist_logits(
    const int* __restrict__ ei, const float* __restrict__ ew,
    const float* __restrict__ ssrc, const float* __restrict__ stgt,
    int* __restrict__ bcnt, float* __restrict__ parr, int E)
{
    __shared__ int lh[256];
    const int tid = threadIdx.x;
    lh[tid] = 0;
    __syncthreads();
    const int base = blockIdx.x * 4096;
    #pragma unroll
    for (int j = 0; j < 4; ++j) {
        int e4 = base + j * 1024 + tid * 4;
        if (e4 + 3 < E) {
            int4 ss = *(const int4*)&ei[e4];
            int4 tt = *(const int4*)&ei[E + e4];
            float4 ww = *(const float4*)&ew[e4];
            float vs0 = ssrc[ss.x], vs1 = ssrc[ss.y], vs2 = ssrc[ss.z], vs3 = ssrc[ss.w];
            float vt0 = stgt[tt.x], vt1 = stgt[tt.y], vt2 = stgt[tt.z], vt3 = stgt[tt.w];
            float4 pp = make_float4(leaky_exp(vs0, vt0, ww.x),
                                    leaky_exp(vs1, vt1, ww.y),
                                    leaky_exp(vs2, vt2, ww.z),
                                    leaky_exp(vs3, vt3, ww.w));
            *(float4*)&parr[e4] = pp;
            atomicAdd(&lh[tt.x >> BKT_SHIFT], 1);
            atomicAdd(&lh[tt.y >> BKT_SHIFT], 1);
            atomicAdd(&lh[tt.z >> BKT_SHIFT], 1);
            atomicAdd(&lh[tt.w >> BKT_SHIFT], 1);
        } else {
            for (int e = e4; e < E; ++e) {
                int s = ei[e], t = ei[E + e];
                parr[e] = leaky_exp(ssrc[s], stgt[t], ew[e]);
                atomicAdd(&lh[t >> BKT_SHIFT], 1);
            }
        }
    }
    __syncthreads();
    if (lh[tid] > 0) atomicAdd(&bcnt[tid], lh[tid]);
}

// ---------------------------------------------------------------------------
// Kernel 3: tiny scan of 256 bucket counts -> bkt_base[257], seed bcur.
// ---------------------------------------------------------------------------
__global__ __launch_bounds__(256) void gat_bscan(
    const int* __restrict__ bcnt, int* __restrict__ bkt_base,
    int* __restrict__ bcur, int E)
{
    __shared__ int lds[256];
    int i = threadIdx.x;
    lds[i] = bcnt[i];
    __syncthreads();
    if (i == 0) {
        int acc = 0;
        for (int j = 0; j < 256; ++j) { int c = lds[j]; lds[j] = acc; acc += c; }
    }
    __syncthreads();
    bkt_base[i] = lds[i];
    bcur[i] = lds[i];
    if (i == 0) bkt_base[256] = E;
}

// ---------------------------------------------------------------------------
// Kernel 4 (pass A): LDS-binned coarse scatter (R8 structure, CAP=24 ->
// 48 KB staging -> 3 blocks/CU). Reads precomputed p (no gathers, no expf);
// 4 edges per batch for MLP. Flushes contiguous runs -> full-line writes.
// ---------------------------------------------------------------------------
__global__ __launch_bounds__(256) void gat_binA(
    const int* __restrict__ ei, const float* __restrict__ parr,
    int* __restrict__ bcur, int2* __restrict__ staged_g, int E)
{
    __shared__ int2 staged[256 * CAP];   // 48 KB
    __shared__ int fill[256];
    __shared__ int gpos[256];
    const int tid = threadIdx.x;
    fill[tid] = 0;
    __syncthreads();

    const int base = blockIdx.x * PASSA_CHUNK;
    #pragma unroll
    for (int j = 0; j < PASSA_CHUNK / 1024; ++j) {
        int e4 = base + j * 1024 + tid * 4;
        if (e4 + 3 < E) {
            int4 ss = *(const int4*)&ei[e4];
            int4 tt = *(const int4*)&ei[E + e4];
            float4 pp = *(const float4*)&parr[e4];
            int sv[4] = {ss.x, ss.y, ss.z, ss.w};
            int tv[4] = {tt.x, tt.y, tt.z, tt.w};
            float pv[4] = {pp.x, pp.y, pp.z, pp.w};
            #pragma unroll
            for (int u = 0; u < 4; ++u) {
                int b = tv[u] >> BKT_SHIFT;
                int2 rec = make_int2(sv[u] | ((tv[u] & (BKT_SIZE - 1)) << 17),
                                     __float_as_int(pv[u]));
                int pos = atomicAdd(&fill[b], 1);
                if (pos < CAP) staged[b * CAP + pos] = rec;
                else           staged_g[atomicAdd(&bcur[b], 1)] = rec;
            }
        } else {
            for (int e = e4; e < E; ++e) {
                int s = ei[e], t = ei[E + e];
                int b = t >> BKT_SHIFT;
                int2 rec = make_int2(s | ((t & (BKT_SIZE - 1)) << 17),
                                     __float_as_int(parr[e]));
                int pos = atomicAdd(&fill[b], 1);
                if (pos < CAP) staged[b * CAP + pos] = rec;
                else           staged_g[atomicAdd(&bcur[b], 1)] = rec;
            }
        }
    }
    __syncthreads();

    int f = min(fill[tid], CAP);
    gpos[tid] = (f > 0) ? atomicAdd(&bcur[tid], f) : 0;
    __syncthreads();

    for (int i = tid; i < 256 * CAP; i += 256) {
        int b = i / CAP;
        int r = i - b * CAP;
        if (r < min(fill[b], CAP))
            staged_g[gpos[b] + r] = staged[i];
    }
}

// ---------------------------------------------------------------------------
// Kernel 5 (pass B): fine sort within a bucket, all in LDS.
// ---------------------------------------------------------------------------
__global__ __launch_bounds__(256) void gat_binB(
    const int2* __restrict__ staged_g, const int* __restrict__ bkt_base,
    int* __restrict__ row_ptr, int2* __restrict__ sorted_sp, int N, int E)
{
    __shared__ int lcnt[BKT_SIZE];
    __shared__ int lcur[BKT_SIZE];
    __shared__ int lscan[256];

    const int b = blockIdx.x;
    const int tid = threadIdx.x;
    const int tbase = b << BKT_SHIFT;
    const int beg = bkt_base[b];
    const int end = bkt_base[b + 1];

    lcnt[tid] = 0; lcnt[tid + 256] = 0;
    __syncthreads();

    for (int i = beg + tid; i < end; i += 256) {
        int tl = (staged_g[i].x >> 17) & (BKT_SIZE - 1);
        atomicAdd(&lcnt[tl], 1);
    }
    __syncthreads();

    int c0 = lcnt[2 * tid], c1 = lcnt[2 * tid + 1];
    int pair = c0 + c1;
    lscan[tid] = pair;
    __syncthreads();
    for (int off = 1; off < 256; off <<= 1) {
        int t = (tid >= off) ? lscan[tid - off] : 0;
        __syncthreads();
        lscan[tid] += t;
        __syncthreads();
    }
    int excl = lscan[tid] - pair;
    lcur[2 * tid]     = beg + excl;
    lcur[2 * tid + 1] = beg + excl + c0;
    __syncthreads();

    #pragma unroll
    for (int j = 0; j < 2; ++j) {
        int tl = tid + j * 256;
        int g = tbase + tl;
        if (g < N) row_ptr[g] = lcur[tl];
    }
    if (tid == 0 && b == gridDim.x - 1) row_ptr[N] = E;

    for (int i = beg + tid; i < end; i += 256) {
        int2 rec = staged_g[i];
        int tl = (rec.x >> 17) & (BKT_SIZE - 1);
        int pos = atomicAdd(&lcur[tl], 1);
        sorted_sp[pos] = make_int2(rec.x & 0x1FFFF, rec.y);
    }
}

// ---------------------------------------------------------------------------
// Kernel 6: segmented reduction. One wave per target; 8 sub-groups of 8 lanes,
// each sub owns one edge per iteration; each lane loads ushort8 (16 B).
// ---------------------------------------------------------------------------
__global__ __launch_bounds__(256) void gat_aggregate_csr(
    const int* __restrict__ row_ptr, const int2* __restrict__ sorted_sp,
    const unsigned short* __restrict__ Wh, float* __restrict__ out, int N)
{
    int t = blockIdx.x * 4 + (threadIdx.x >> 6);
    if (t >= N) return;
    int lane = threadIdx.x & 63;
    int sub  = lane >> 3;    // edge slot 0..7
    int c8   = lane & 7;     // channel block: channels c8*8 .. c8*8+7

    int beg = row_ptr[t], end = row_ptr[t + 1];

    float acc[8] = {0.f, 0.f, 0.f, 0.f, 0.f, 0.f, 0.f, 0.f};
    float psum = 0.f;

    int i = beg + sub;
    for (; i + 8 < end; i += 16) {
        int2 spA = sorted_sp[i];
        int2 spB = sorted_sp[i + 8];
        float pA = __int_as_float(spA.y);
        float pB = __int_as_float(spB.y);
        ushortx8 wA = *(const ushortx8*)&Wh[(size_t)spA.x * DOUT + c8 * 8];
        ushortx8 wB = *(const ushortx8*)&Wh[(size_t)spB.x * DOUT + c8 * 8];
        #pragma unroll
        for (int j = 0; j < 8; ++j) acc[j] += pA * bf16_to_f32(wA[j]);
        psum += pA;
        #pragma unroll
        for (int j = 0; j < 8; ++j) acc[j] += pB * bf16_to_f32(wB[j]);
        psum += pB;
    }
    if (i < end) {
        int2 sp = sorted_sp[i];
        float p = __int_as_float(sp.y);
        ushortx8 w = *(const ushortx8*)&Wh[(size_t)sp.x * DOUT + c8 * 8];
        #pragma unroll
        for (int j = 0; j < 8; ++j) acc[j] += p * bf16_to_f32(w[j]);
        psum += p;
    }

    #pragma unroll
    for (int m = 8; m < 64; m <<= 1) {
        #pragma unroll
        for (int j = 0; j < 8; ++j) acc[j] += __shfl_xor(acc[j], m);
        psum += __shfl_xor(psum, m);
    }

    if (sub == 0) {
        float inv = 1.0f / (psum + EPSV);
        float4 o0 = make_float4(acc[0] * inv, acc[1] * inv, acc[2] * inv, acc[3] * inv);
        float4 o1 = make_float4(acc[4] * inv, acc[5] * inv, acc[6] * inv, acc[7] * inv);
        *(float4*)&out[(size_t)t * DOUT + c8 * 8]     = o0;
        *(float4*)&out[(size_t)t * DOUT + c8 * 8 + 4] = o1;
    }
}

extern "C" void kernel_launch(void* const* d_in, const int* in_sizes, int n_in,
                              void* d_out, int out_size, void* d_ws, size_t ws_size,
                              hipStream_t stream) {
    const float* x  = (const float*)d_in[0];
    const int*   ei = (const int*)d_in[1];
    const float* ew = (const float*)d_in[2];
    const float* W  = (const float*)d_in[3];
    const float* a  = (const float*)d_in[4];
    const int N = in_sizes[0] / DIN;
    const int E = in_sizes[2];
    float* out = (float*)d_out;

    char* wsb = (char*)d_ws;
    unsigned short* Wh = (unsigned short*)wsb;      wsb += (size_t)N * DOUT * 2;
    float* ssrc      = (float*)wsb;                 wsb += (size_t)N * 4;
    float* stgt      = (float*)wsb;                 wsb += (size_t)N * 4;
    int*   row_ptr   = (int*)wsb;                   wsb += (size_t)(N + 1) * 4;
    int*   bcnt      = (int*)wsb;                   wsb += 257 * 4;
    int*   bkt_base  = (int*)wsb;                   wsb += 257 * 4;
    int*   bcur      = (int*)wsb;                   wsb += 256 * 4;
    wsb = (char*)(((uintptr_t)wsb + 15) & ~(uintptr_t)15);
    float* parr      = (float*)wsb;                 wsb += (size_t)E * 4;
    int2*  staged_g  = (int2*)wsb;                  wsb += (size_t)E * 8;
    int2*  sorted_sp = (int2*)wsb;                  wsb += (size_t)E * 8;

    const int nbk = (N + BKT_SIZE - 1) >> BKT_SHIFT;

    (void)hipMemsetAsync(bcnt, 0, 257 * sizeof(int), stream);

    gat_gemm_scores<<<(N + 63) / 64, 256, 0, stream>>>(x, W, a, Wh, ssrc, stgt, N);
    gat_bhist_logits<<<(E + 4095) / 4096, 256, 0, stream>>>(ei, ew, ssrc, stgt,
                                                            bcnt, parr, E);
    gat_bscan <<<1, 256, 0, stream>>>(bcnt, bkt_base, bcur, E);
    gat_binA  <<<(E + PASSA_CHUNK - 1) / PASSA_CHUNK, 256, 0, stream>>>(
                  ei, parr, bcur, staged_g, E);
    gat_binB  <<<nbk, 256, 0, stream>>>(staged_g, bkt_base, row_ptr, sorted_sp, N, E);
    gat_aggregate_csr<<<(N + 3) / 4, 256, 0, stream>>>(row_ptr, sorted_sp, Wh, out, N);
}